// Round 6
// baseline (155.154 us; speedup 1.0000x reference)
//
#include <hip/hip_runtime.h>
#include <hip/hip_bf16.h>

// Problem constants: B=4, C=256, H=W=64, KS=3, N=9
#define HW    4096
#define J_TOT 16384   // B*H*W
#define K_TOT 2304    // 9*256
#define C_CH  256

typedef unsigned short u16;
typedef unsigned int   u32;
typedef __attribute__((ext_vector_type(8))) short short8;   // 8 bf16, MFMA A/B frag
typedef __attribute__((ext_vector_type(4))) float f32x4;    // MFMA C/D frag
typedef __attribute__((ext_vector_type(8))) unsigned short us8;
typedef __attribute__((ext_vector_type(4))) unsigned short us4;

__device__ __forceinline__ float b2f(u16 u) { return __uint_as_float(((u32)u) << 16); }
__device__ __forceinline__ u16 f2b(float x) {             // RNE f32->bf16
  u32 u = __float_as_uint(x);
  u += 0x7FFFu + ((u >> 16) & 1u);
  return (u16)(u >> 16);
}
__device__ __forceinline__ float blo(u32 u) { return __uint_as_float(u << 16); }
__device__ __forceinline__ float bhi(u32 u) { return __uint_as_float(u & 0xFFFF0000u); }

// bilinear combine of 4 bf16x8 corner vectors -> bf16x8, pairwise f32 math
__device__ __forceinline__ us8 interp8(us8 r0, us8 r1, us8 r2, us8 r3,
                                       float g0, float g1, float g2, float g3) {
  us8 o;
  const u32* p0 = (const u32*)&r0;
  const u32* p1 = (const u32*)&r1;
  const u32* p2 = (const u32*)&r2;
  const u32* p3 = (const u32*)&r3;
  u32* po = (u32*)&o;
#pragma unroll
  for (int i = 0; i < 4; i++) {
    u32 a = p0[i], b = p1[i], c = p2[i], d = p3[i];
    float2 v;
    v.x = g0 * blo(a) + g1 * blo(b) + g2 * blo(c) + g3 * blo(d);
    v.y = g0 * bhi(a) + g1 * bhi(b) + g2 * bhi(c) + g3 * bhi(d);
    __hip_bfloat162 pk = __float22bfloat162_rn(v);
    po[i] = *reinterpret_cast<u32*>(&pk);
  }
  return o;
}

// per-block dtype detection from feature[0..4095] halfwords (1=bf16, 0=f32)
__device__ __forceinline__ int detect_bf16(const u16* f, int t, int nthr, int* cnt) {
  if (t == 0) *cnt = 0;
  __syncthreads();
  int hits = 0;
  for (int i = t; i < 2048; i += nthr) {
    u16 u = f[2 * i];
    int e = (u >> 7) & 0xFF;
    hits += (e >= 100 && e <= 141) ? 1 : 0;
  }
  atomicAdd(cnt, hits);
  __syncthreads();
  return (*cnt > 1024) ? 1 : 0;
}

// ---------------------------------------------------------------------------
// Kernel 1: PREP (self-detecting). Blocks 0..4095: feature -> channels-last
// bf16 ftr[b][hw][c]. Blocks 4096..6399: weight (o,c,3,3) -> Wr[o][n*256+c].
// ---------------------------------------------------------------------------
__global__ __launch_bounds__(256) void k_prep(const void* __restrict__ featv,
                                              const void* __restrict__ wv,
                                              u16* __restrict__ ftr,
                                              u16* __restrict__ Wr) {
  __shared__ int cnt;
  __shared__ u16 tile[32][33];
  int t = threadIdx.x;
  int isbf = detect_bf16((const u16*)featv, t, 256, &cnt);
  int bi = blockIdx.x;
  if (bi < 4096) {
    int b = bi >> 10;
    int y = (bi >> 7) & 7;
    int x = bi & 127;
    int hw0 = x << 5;
    int c0 = y << 5;
    int tx = t & 31, ty = t >> 5;
    if (isbf) {
      const u16* f = (const u16*)featv;
#pragma unroll
      for (int i = 0; i < 4; i++) {
        int c = c0 + ty + i * 8;
        tile[ty + i * 8][tx] = f[(((size_t)(b * C_CH + c)) << 12) + hw0 + tx];
      }
    } else {
      const float* f = (const float*)featv;
#pragma unroll
      for (int i = 0; i < 4; i++) {
        int c = c0 + ty + i * 8;
        tile[ty + i * 8][tx] = f2b(f[(((size_t)(b * C_CH + c)) << 12) + hw0 + tx]);
      }
    }
    __syncthreads();
#pragma unroll
    for (int i = 0; i < 4; i++) {
      int hw = hw0 + ty + i * 8;
      ftr[(((size_t)(b * HW + hw)) << 8) + c0 + tx] = tile[tx][ty + i * 8];
    }
  } else {
    int idx = (bi - 4096) * 256 + t;             // = o*2304 + n*256 + c
    int c = idx & 255;
    int n = (idx >> 8) % 9;
    int o = idx / K_TOT;
    int src = (o * 256 + c) * 9 + n;
    if (isbf) Wr[idx] = ((const u16*)wv)[src];
    else      Wr[idx] = f2b(((const float*)wv)[src]);
  }
}

// ---------------------------------------------------------------------------
// Kernel 2: FUSED deform-gather + GEMM + epilogue, pipelined double-buffer.
// Grid 256 blocks x 512 threads (8 waves, 2/SIMD). Block = 64 px x 256 o.
// Wave tile 64j x 32o: 2x4 frags of 16x16x32 -> 8 MFMA/kc.
// Per n (ONE barrier): load(n+1 group0) -> MFMA(n, kc0..3) -> interp g0 +
// load(n+1 group1) -> MFMA(n, kc4..7) -> interp g1 -> barrier. Producer
// loads sit in flight under ~32 MFMAs + ds_reads. A direct from L2 Wr.
// ---------------------------------------------------------------------------
__global__ __launch_bounds__(512) void k_fused(const u16* __restrict__ Wr,
                                               const u16* __restrict__ ftr,
                                               const void* __restrict__ offv,
                                               const void* __restrict__ featv,
                                               void* __restrict__ outv) {
  __shared__ u16 Bs[2][64 * 256];   // 2 x 32 KB, row = px, 32 chunks of 16B
  __shared__ u16 cq[9][64][4];      // 4.5 KB, packed corner idx (x-1)*64+(y-1)
  __shared__ float cg[9][64][4];    // 9 KB, corner weights
  __shared__ int cnt;
  int t = threadIdx.x;
  int isbf = detect_bf16((const u16*)featv, t, 512, &cnt);

  int jb = blockIdx.x << 6;
  int b  = jb >> 12;                // block = one h-row of one batch
  int hw0 = jb & (HW - 1);
  int wave = t >> 6, lane = t & 63;
  int lr = lane & 15, lk = lane >> 4;
  int lane16 = t & 15, grp16 = t >> 4;   // producer identity (32 px-groups)

  // ---- Phase 0: corner math for all (px, n), 576 tasks over 512 threads ----
  for (int task = t; task < 576; task += 512) {
    int px = task & 63, n = task >> 6;
    int phw = hw0 + px;
    int ph = phw >> 6, pw = phw & 63;
    size_t obi = (((size_t)(b * 18 + n)) << 12) + phw;
    float ox, oy;
    if (isbf) {
      const u16* po = (const u16*)offv;
      ox = b2f(po[obi]);
      oy = b2f(po[obi + (9u << 12)]);
    } else {
      const float* po = (const float*)offv;
      ox = po[obi];
      oy = po[obi + (9u << 12)];
    }
    int ki = n / 3, kj = n % 3;
    float sx = (float)(ph + ki) + ox;
    float sy = (float)(pw + kj) + oy;
    float fx = floorf(sx), fy = floorf(sy);
    float qltx = fminf(fmaxf(fx, 0.f), 65.f);
    float qlty = fminf(fmaxf(fy, 0.f), 65.f);
    float qrbx = fminf(fmaxf(fx + 1.f, 0.f), 65.f);
    float qrby = fminf(fmaxf(fy + 1.f, 0.f), 65.f);
    float pcx = fminf(fmaxf(sx, 0.f), 65.f);
    float pcy = fminf(fmaxf(sy, 0.f), 65.f);
    float dltx = 1.f + (qltx - pcx);
    float drbx = 1.f - (qrbx - pcx);
    float dlty = 1.f + (qlty - pcy);
    float drby = 1.f - (qrby - pcy);
    float g0 = dltx * dlty;   // (q_lt_x, q_lt_y)
    float g1 = drbx * drby;   // (q_rb_x, q_rb_y)
    float g2 = dltx * drby;   // (q_lt_x, q_rb_y)
    float g3 = drbx * dlty;   // (q_rb_x, q_lt_y)
    int x0 = (int)qltx, y0 = (int)qlty, x1 = (int)qrbx, y1 = (int)qrby;
    int v0 = (x0 >= 1 && x0 <= 64 && y0 >= 1 && y0 <= 64);
    int v1 = (x1 >= 1 && x1 <= 64 && y1 >= 1 && y1 <= 64);
    int v2 = (x0 >= 1 && x0 <= 64 && y1 >= 1 && y1 <= 64);
    int v3 = (x1 >= 1 && x1 <= 64 && y0 >= 1 && y0 <= 64);
    cq[n][px][0] = v0 ? (u16)(((x0 - 1) << 6) + (y0 - 1)) : (u16)0;
    cq[n][px][1] = v1 ? (u16)(((x1 - 1) << 6) + (y1 - 1)) : (u16)0;
    cq[n][px][2] = v2 ? (u16)(((x0 - 1) << 6) + (y1 - 1)) : (u16)0;
    cq[n][px][3] = v3 ? (u16)(((x1 - 1) << 6) + (y0 - 1)) : (u16)0;
    cg[n][px][0] = v0 ? g0 : 0.f;
    cg[n][px][1] = v1 ? g1 : 0.f;
    cg[n][px][2] = v2 ? g2 : 0.f;
    cg[n][px][3] = v3 ? g3 : 0.f;
  }

  f32x4 acc[2][4];   // [oi][ji]
  f32x4 zero = {0.f, 0.f, 0.f, 0.f};
#pragma unroll
  for (int i = 0; i < 2; i++)
#pragma unroll
    for (int j = 0; j < 4; j++) acc[i][j] = zero;

  // A fragment base pointers (o = wave*32 + oi*16 + lr, K-major)
  const u16* awp[2];
  awp[0] = Wr + (size_t)(wave * 32 + lr) * K_TOT + lk * 8;
  awp[1] = awp[0] + (size_t)16 * K_TOT;

  int bbase = b << 12;

  // producer: 4 chunks/thread/n: u = (s<<1)|half, px = grp16 + s*32
  us8 P[2][4];   // [u within group][corner]

  auto loadGroup = [&](int n1, int g) {
#pragma unroll
    for (int u = 0; u < 2; u++) {
      int px = grp16 + g * 32;
      int c16 = u * 16 + lane16;
      int ch = c16 * 8;
      us4 q = *(const us4*)&cq[n1][px][0];
      P[u][0] = *(const us8*)(ftr + ((bbase + q.x) << 8) + ch);
      P[u][1] = *(const us8*)(ftr + ((bbase + q.y) << 8) + ch);
      P[u][2] = *(const us8*)(ftr + ((bbase + q.z) << 8) + ch);
      P[u][3] = *(const us8*)(ftr + ((bbase + q.w) << 8) + ch);
    }
  };
  auto interpGroup = [&](int n1, int g, u16* dstp) {
#pragma unroll
    for (int u = 0; u < 2; u++) {
      int px = grp16 + g * 32;
      int c16 = u * 16 + lane16;
      float4 g4 = *(const float4*)&cg[n1][px][0];
      us8 ov = interp8(P[u][0], P[u][1], P[u][2], P[u][3], g4.x, g4.y, g4.z, g4.w);
      int cs = c16 ^ (px & 7);
      *(us8*)(&Bs[(n1) & 1][px * 256 + cs * 8]) = ov;
      (void)dstp;
    }
  };
  auto consume4 = [&](int n, int kc0) {
    const u16* srcp = Bs[n & 1];
#pragma unroll
    for (int k2 = 0; k2 < 4; k2++) {
      int kc = kc0 + k2;
      short8 Af[2], Bf[4];
#pragma unroll
      for (int oi = 0; oi < 2; oi++)
        Af[oi] = *(const short8*)(awp[oi] + (n << 8) + kc * 32);
#pragma unroll
      for (int ji = 0; ji < 4; ji++) {
        int row = ji * 16 + lr;
        int cs = (kc * 4 + lk) ^ (row & 7);
        Bf[ji] = *(const short8*)(&srcp[row * 256 + cs * 8]);
      }
#pragma unroll
      for (int oi = 0; oi < 2; oi++)
#pragma unroll
        for (int ji = 0; ji < 4; ji++)
          acc[oi][ji] = __builtin_amdgcn_mfma_f32_16x16x32_bf16(Af[oi], Bf[ji], acc[oi][ji], 0, 0, 0);
    }
  };

  __syncthreads();   // tables ready

  // prologue: produce panel 0
  loadGroup(0, 0); interpGroup(0, 0, nullptr);
  loadGroup(0, 1); interpGroup(0, 1, nullptr);
  __syncthreads();

  for (int n = 0; n < 9; n++) {
    if (n < 8) loadGroup(n + 1, 0);
    consume4(n, 0);
    if (n < 8) { interpGroup(n + 1, 0, nullptr); loadGroup(n + 1, 1); }
    consume4(n, 4);
    if (n < 8) interpGroup(n + 1, 1, nullptr);
    __syncthreads();
  }

  // ---- epilogue: D col = lane&15 (j), row = (lane>>4)*4 + r (o) ----
#pragma unroll
  for (int oi = 0; oi < 2; oi++) {
#pragma unroll
    for (int ji = 0; ji < 4; ji++) {
      int j = jb + ji * 16 + lr;
      int hww = j & (HW - 1);
      int o0 = wave * 32 + oi * 16 + lk * 4;
#pragma unroll
      for (int r = 0; r < 4; r++) {
        size_t oidx = (((size_t)(b * C_CH + o0 + r)) << 12) + hww;
        float v = acc[oi][ji][r];
        v = fmaxf(v, 0.f);
        float ft = isbf ? b2f(((const u16*)featv)[oidx]) : ((const float*)featv)[oidx];
        v = fmaxf(v + ft, 0.f);
        if (isbf) ((u16*)outv)[oidx] = f2b(v);
        else      ((float*)outv)[oidx] = v;
      }
    }
  }
}

extern "C" void kernel_launch(void* const* d_in, const int* in_sizes, int n_in,
                              void* d_out, int out_size, void* d_ws, size_t ws_size,
                              hipStream_t stream) {
  const void* feat = d_in[0];
  const void* offs = d_in[1];
  const void* wght = d_in[2];

  // workspace layout (256B-aligned sections), total ~9.6 MB
  const size_t off_wr   = 0;                            // bf16 Wr, 1.125 MB
  const size_t off_ftr  = off_wr + (size_t)1179648;     // bf16 channels-last feature, 8 MB
  const size_t need     = off_ftr + (size_t)8388608;
  if (ws_size < need) return;  // insufficient scratch; cannot run

  char* ws = (char*)d_ws;
  u16* Wr   = (u16*)(ws + off_wr);
  u16* ftr  = (u16*)(ws + off_ftr);

  k_prep<<<4096 + 2304, 256, 0, stream>>>(feat, wght, ftr, Wr);
  k_fused<<<J_TOT / 64, 512, 0, stream>>>(Wr, ftr, offs, feat, d_out);
}